// Round 1
// baseline (3133.648 us; speedup 1.0000x reference)
//
#include <hip/hip_runtime.h>

#define BB 4
#define NN 16384
#define CC 64
#define NPOINT 1024
#define NSAMPLE 32
#define PPT 16   // points per thread in FPS: NN / 1024

// ---------------------------------------------------------------------------
// K1: Farthest point sampling. One block per batch, 1024 threads, 16 pts each.
// Writes new_xyz (the gathered centroid coords) directly to d_out.
// Bit-exact vs reference: contract(off), left-assoc sum, first-index argmax.
// ---------------------------------------------------------------------------
__global__ __launch_bounds__(1024) void fps_kernel(const float* __restrict__ xyz,
                                                   float* __restrict__ new_xyz) {
    #pragma clang fp contract(off)
    const int b   = blockIdx.x;
    const int tid = threadIdx.x;
    const float* bx = xyz + (size_t)b * NN * 3;

    float px[PPT], py[PPT], pz[PPT], d[PPT];
    #pragma unroll
    for (int j = 0; j < PPT; ++j) {
        const int p = tid * PPT + j;
        px[j] = bx[p * 3 + 0];
        py[j] = bx[p * 3 + 1];
        pz[j] = bx[p * 3 + 2];
        d[j]  = 1e10f;   // matches jnp.full(..., 10000000000.0, f32)
    }

    __shared__ float s_val[16];
    __shared__ int   s_idx[16];
    __shared__ float s_cx, s_cy, s_cz;

    if (tid == 0) { s_cx = bx[0]; s_cy = bx[1]; s_cz = bx[2]; }
    __syncthreads();

    float* outb = new_xyz + (size_t)b * NPOINT * 3;

    for (int it = 0; it < NPOINT; ++it) {
        const float cx = s_cx, cy = s_cy, cz = s_cz;
        if (tid == 0) {
            outb[it * 3 + 0] = cx;
            outb[it * 3 + 1] = cy;
            outb[it * 3 + 2] = cz;
        }

        // local distance update + local argmax (ascending j => first-index wins)
        float best = -1.0f;
        int   bj   = 0;
        #pragma unroll
        for (int j = 0; j < PPT; ++j) {
            const float dx = px[j] - cx;
            const float dy = py[j] - cy;
            const float dz = pz[j] - cz;
            const float t  = dx * dx + dy * dy + dz * dz;  // no FMA (contract off)
            const float nd = fminf(d[j], t);
            d[j] = nd;
            const bool gt = nd > best;
            bj   = gt ? j  : bj;
            best = gt ? nd : best;
        }
        int bidx = tid * PPT + bj;

        // wave (64-lane) butterfly argmax; tie -> smaller global index
        #pragma unroll
        for (int m = 32; m >= 1; m >>= 1) {
            const float ov = __shfl_xor(best, m, 64);
            const int   oi = __shfl_xor(bidx, m, 64);
            if (ov > best || (ov == best && oi < bidx)) { best = ov; bidx = oi; }
        }
        if ((tid & 63) == 0) {
            s_val[tid >> 6] = best;
            s_idx[tid >> 6] = bidx;
        }
        __syncthreads();

        if (tid == 0) {
            float bv = s_val[0];
            int   bi = s_idx[0];
            #pragma unroll
            for (int w = 1; w < 16; ++w) {
                const float ov = s_val[w];
                const int   oi = s_idx[w];
                if (ov > bv || (ov == bv && oi < bi)) { bv = ov; bi = oi; }
            }
            s_cx = bx[bi * 3 + 0];
            s_cy = bx[bi * 3 + 1];
            s_cz = bx[bi * 3 + 2];
        }
        __syncthreads();
    }
}

// ---------------------------------------------------------------------------
// K2: Ball query. One wave per query; ordered first-32 selection via ballot,
// early exit once 32 found. Exact arithmetic (contract off, rad2 = (float)0.04).
// ---------------------------------------------------------------------------
__global__ __launch_bounds__(256) void ballq_kernel(const float* __restrict__ xyz,
                                                    const float* __restrict__ new_xyz,
                                                    int* __restrict__ gidx) {
    #pragma clang fp contract(off)
    const int lane = threadIdx.x & 63;
    const int q    = blockIdx.x * 4 + (threadIdx.x >> 6);
    const int b    = q >> 10;                  // NPOINT = 1024
    const float* bx = xyz + (size_t)b * NN * 3;
    const float* nx = new_xyz + (size_t)q * 3;
    const float cx = nx[0], cy = nx[1], cz = nx[2];
    const float rad2 = 0.04f;  // f32 cast of python double 0.2**2 — NOT 0.2f*0.2f

    int* out  = gidx + (size_t)q * NSAMPLE;
    int taken = 0;
    int first = NN - 1;  // used only if zero neighbors (never in practice)

    for (int chunk = 0; chunk < NN / 64 && taken < NSAMPLE; ++chunk) {
        const int   i  = chunk * 64 + lane;
        const float dx = cx - bx[i * 3 + 0];
        const float dy = cy - bx[i * 3 + 1];
        const float dz = cz - bx[i * 3 + 2];
        const float t  = dx * dx + dy * dy + dz * dz;
        const bool ok  = !(t > rad2);          // keep iff NOT (d > r^2)
        const unsigned long long m = __ballot(ok);
        const int cnt = __popcll(m);
        if (taken == 0 && cnt > 0) first = chunk * 64 + (__ffsll((long long)m) - 1);
        if (ok) {
            const int rank = taken + __popcll(m & ((1ull << lane) - 1ull));
            if (rank < NSAMPLE) out[rank] = i;
        }
        taken += cnt;
    }
    const int sat = taken < NSAMPLE ? taken : NSAMPLE;
    if (lane >= sat && lane < NSAMPLE) out[lane] = (taken > 0) ? first : (NN - 1);
}

// ---------------------------------------------------------------------------
// K3: gather feats -> LDS, MLP1 (67->64) + relu, MLP2 (64->128) + relu,
// max over the 32 samples. One 256-thread block per query. FMA allowed
// (reference einsum goes through a GEMM — accumulation order is free).
// ---------------------------------------------------------------------------
__global__ __launch_bounds__(256) void mlp_kernel(const float* __restrict__ xyz,
                                                  const float* __restrict__ points,
                                                  const float* __restrict__ w1,
                                                  const float* __restrict__ b1,
                                                  const float* __restrict__ w2,
                                                  const float* __restrict__ b2,
                                                  const float* __restrict__ new_xyz,
                                                  const int*   __restrict__ gidx,
                                                  float* __restrict__ new_points) {
    __shared__ __align__(16) float feats[32][68];  // [0..2]=xyz-norm, [3]=pad, [4..67]=points
    __shared__ __align__(16) float h1s[32][64];
    __shared__ float pmax[2][128];

    const int q = blockIdx.x;
    const int b = q >> 10;
    const int t = threadIdx.x;

    // ---- phase A: gather features into LDS (8 threads per sample row) ----
    {
        const int k  = t >> 3;
        const int l8 = t & 7;
        const int gi = gidx[q * 32 + k];
        const float* prow = points + ((size_t)b * NN + gi) * CC;
        const float4 v0 = *(const float4*)(prow + l8 * 8);
        const float4 v1 = *(const float4*)(prow + l8 * 8 + 4);
        *(float4*)&feats[k][4 + l8 * 8] = v0;
        *(float4*)&feats[k][8 + l8 * 8] = v1;
        if (l8 == 0) {
            const float* pr = xyz + ((size_t)b * NN + gi) * 3;
            const float* nr = new_xyz + (size_t)q * 3;
            feats[k][0] = pr[0] - nr[0];
            feats[k][1] = pr[1] - nr[1];
            feats[k][2] = pr[2] - nr[2];
        }
    }

    // w1 row in registers (c1 = t & 63), loaded while feats land in LDS
    const int c1 = t & 63;
    float w1r[67];
    #pragma unroll
    for (int j = 0; j < 67; ++j) w1r[j] = w1[c1 * 67 + j];
    const float bb1 = b1[c1];
    __syncthreads();

    // ---- phase B: layer 1. Wave-uniform k => LDS broadcast reads ----
    const int kg = t >> 6;   // wave id, 0..3
    #pragma unroll
    for (int kk = 0; kk < 8; ++kk) {
        const int kr = kg * 8 + kk;
        float acc = bb1;
        acc += feats[kr][0] * w1r[0] + feats[kr][1] * w1r[1] + feats[kr][2] * w1r[2];
        #pragma unroll
        for (int j = 0; j < 64; j += 4) {
            const float4 f = *(const float4*)&feats[kr][4 + j];
            acc += f.x * w1r[3 + j] + f.y * w1r[4 + j] + f.z * w1r[5 + j] + f.w * w1r[6 + j];
        }
        h1s[kr][c1] = fmaxf(acc, 0.0f);
    }

    // w2 row in registers (o2 = t & 127); k split in halves across thread groups
    const int o2 = t & 127;
    const int kh = t >> 7;   // 0 or 1
    float w2r[64];
    #pragma unroll
    for (int j = 0; j < 64; ++j) w2r[j] = w2[o2 * 64 + j];
    const float bb2 = b2[o2];
    __syncthreads();

    // ---- phase C: layer 2 + running max over k ----
    float mx = -INFINITY;
    #pragma unroll
    for (int kk = 0; kk < 16; ++kk) {
        const int kr = kh * 16 + kk;
        float acc = bb2;
        #pragma unroll
        for (int j = 0; j < 64; j += 4) {
            const float4 h = *(const float4*)&h1s[kr][j];
            acc += h.x * w2r[j] + h.y * w2r[j + 1] + h.z * w2r[j + 2] + h.w * w2r[j + 3];
        }
        mx = fmaxf(mx, fmaxf(acc, 0.0f));
    }
    pmax[kh][o2] = mx;
    __syncthreads();
    if (t < 128) {
        new_points[(size_t)q * 128 + t] = fmaxf(pmax[0][t], pmax[1][t]);
    }
}

// ---------------------------------------------------------------------------
extern "C" void kernel_launch(void* const* d_in, const int* in_sizes, int n_in,
                              void* d_out, int out_size, void* d_ws, size_t ws_size,
                              hipStream_t stream) {
    const float* xyz    = (const float*)d_in[0];   // (4, 16384, 3)
    const float* points = (const float*)d_in[1];   // (4, 16384, 64)
    const float* w1     = (const float*)d_in[2];   // (64, 67)
    const float* b1     = (const float*)d_in[3];   // (64,)
    const float* w2     = (const float*)d_in[4];   // (128, 64)
    const float* b2     = (const float*)d_in[5];   // (128,)
    // d_in[6] = npoint (1024), fixed by the problem setup

    float* out_newxyz    = (float*)d_out;                       // 4*1024*3
    float* out_newpoints = (float*)d_out + (size_t)BB * NPOINT * 3;
    int*   gidx          = (int*)d_ws;                          // 4*1024*32 ints

    fps_kernel<<<BB, 1024, 0, stream>>>(xyz, out_newxyz);
    ballq_kernel<<<(BB * NPOINT) / 4, 256, 0, stream>>>(xyz, out_newxyz, gidx);
    mlp_kernel<<<BB * NPOINT, 256, 0, stream>>>(xyz, points, w1, b1, w2, b2,
                                                out_newxyz, gidx, out_newpoints);
}

// Round 2
// 2617.492 us; speedup vs baseline: 1.1972x; 1.1972x over previous
//
#include <hip/hip_runtime.h>

#define BB 4
#define NN 16384
#define CC 64
#define NPOINT 1024
#define NSAMPLE 32

#define FPS_T 512
#define PPT   32   // NN / FPS_T

// ---------------------------------------------------------------------------
// K1: Farthest point sampling. One block per batch, 512 threads, 32 pts each
// (strided ownership p = j*512 + tid). All state in registers; ONE barrier
// per iteration (double-buffered LDS wave-winner slots); every thread
// redundantly reduces the 8 wave winners and broadcast-loads the winner
// coords from global (same cacheline -> L1/L2 hot).
// Bit-exact vs reference: contract(off), separate mul/add, first-index argmax.
// ---------------------------------------------------------------------------
__global__ __launch_bounds__(FPS_T, 2) void fps_kernel(const float* __restrict__ xyz,
                                                       float* __restrict__ new_xyz) {
    #pragma clang fp contract(off)
    const int b    = blockIdx.x;
    const int tid  = threadIdx.x;
    const int lane = tid & 63;
    const int wv   = tid >> 6;   // 0..7
    const float* bx = xyz + (size_t)b * NN * 3;

    float px[PPT], py[PPT], pz[PPT], d[PPT];
    #pragma unroll
    for (int j = 0; j < PPT; ++j) {
        const int p = j * FPS_T + tid;          // strided: coalesced + ascending idx in j
        px[j] = bx[p * 3 + 0];
        py[j] = bx[p * 3 + 1];
        pz[j] = bx[p * 3 + 2];
        d[j]  = 1e10f;                          // jnp.full(..., 1e10, f32)
    }

    __shared__ float s_val[2][8];
    __shared__ int   s_idx[2][8];

    float cx = bx[0], cy = bx[1], cz = bx[2];   // farthest starts at index 0
    float* outb = new_xyz + (size_t)b * NPOINT * 3;

    for (int it = 0; it < NPOINT; ++it) {
        if (tid == 0) {
            outb[it * 3 + 0] = cx;
            outb[it * 3 + 1] = cy;
            outb[it * 3 + 2] = cz;
        }

        // distance update + local argmax (ascending j => first global index wins)
        float best = -1.0f;
        int   bj   = 0;
        #pragma unroll
        for (int j = 0; j < PPT; ++j) {
            const float dx = px[j] - cx;
            const float dy = py[j] - cy;
            const float dz = pz[j] - cz;
            const float t  = dx * dx + dy * dy + dz * dz;   // no FMA (contract off)
            const float nd = fminf(d[j], t);
            d[j] = nd;
            const bool gt = nd > best;
            bj   = gt ? j  : bj;
            best = gt ? nd : best;
        }
        int bidx = bj * FPS_T + tid;            // global index

        // 64-lane butterfly argmax; tie -> smaller global index
        #pragma unroll
        for (int m = 32; m >= 1; m >>= 1) {
            const float ov = __shfl_xor(best, m, 64);
            const int   oi = __shfl_xor(bidx, m, 64);
            if (ov > best || (ov == best && oi < bidx)) { best = ov; bidx = oi; }
        }
        if (lane == 0) {
            s_val[it & 1][wv] = best;
            s_idx[it & 1][wv] = bidx;
        }
        __syncthreads();

        // every thread reduces the 8 wave winners (broadcast LDS reads)
        float bv = s_val[it & 1][0];
        int   bi = s_idx[it & 1][0];
        #pragma unroll
        for (int w = 1; w < 8; ++w) {
            const float ov = s_val[it & 1][w];
            const int   oi = s_idx[it & 1][w];
            if (ov > bv || (ov == bv && oi < bi)) { bv = ov; bi = oi; }
        }

        // broadcast load of winner coords (same cacheline for all lanes)
        cx = bx[bi * 3 + 0];
        cy = bx[bi * 3 + 1];
        cz = bx[bi * 3 + 2];
    }
}

// ---------------------------------------------------------------------------
// K2: Ball query. One wave per query; ordered first-32 selection via ballot,
// early exit once 32 found. Exact arithmetic (contract off, rad2 = (float)0.04).
// ---------------------------------------------------------------------------
__global__ __launch_bounds__(256) void ballq_kernel(const float* __restrict__ xyz,
                                                    const float* __restrict__ new_xyz,
                                                    int* __restrict__ gidx) {
    #pragma clang fp contract(off)
    const int lane = threadIdx.x & 63;
    const int q    = blockIdx.x * 4 + (threadIdx.x >> 6);
    const int b    = q >> 10;                  // NPOINT = 1024
    const float* bx = xyz + (size_t)b * NN * 3;
    const float* nx = new_xyz + (size_t)q * 3;
    const float cx = nx[0], cy = nx[1], cz = nx[2];
    const float rad2 = 0.04f;  // f32 cast of python double 0.2**2 — NOT 0.2f*0.2f

    int* out  = gidx + (size_t)q * NSAMPLE;
    int taken = 0;
    int first = NN - 1;  // used only if zero neighbors (never in practice)

    for (int chunk = 0; chunk < NN / 64 && taken < NSAMPLE; ++chunk) {
        const int   i  = chunk * 64 + lane;
        const float dx = cx - bx[i * 3 + 0];
        const float dy = cy - bx[i * 3 + 1];
        const float dz = cz - bx[i * 3 + 2];
        const float t  = dx * dx + dy * dy + dz * dz;
        const bool ok  = !(t > rad2);          // keep iff NOT (d > r^2)
        const unsigned long long m = __ballot(ok);
        const int cnt = __popcll(m);
        if (taken == 0 && cnt > 0) first = chunk * 64 + (__ffsll((long long)m) - 1);
        if (ok) {
            const int rank = taken + __popcll(m & ((1ull << lane) - 1ull));
            if (rank < NSAMPLE) out[rank] = i;
        }
        taken += cnt;
    }
    const int sat = taken < NSAMPLE ? taken : NSAMPLE;
    if (lane >= sat && lane < NSAMPLE) out[lane] = (taken > 0) ? first : (NN - 1);
}

// ---------------------------------------------------------------------------
// K3: gather feats -> LDS, MLP1 (67->64) + relu, MLP2 (64->128) + relu,
// max over the 32 samples. One 256-thread block per query. FMA allowed
// (reference einsum goes through a GEMM — accumulation order is free).
// ---------------------------------------------------------------------------
__global__ __launch_bounds__(256) void mlp_kernel(const float* __restrict__ xyz,
                                                  const float* __restrict__ points,
                                                  const float* __restrict__ w1,
                                                  const float* __restrict__ b1,
                                                  const float* __restrict__ w2,
                                                  const float* __restrict__ b2,
                                                  const float* __restrict__ new_xyz,
                                                  const int*   __restrict__ gidx,
                                                  float* __restrict__ new_points) {
    __shared__ __align__(16) float feats[32][68];  // [0..2]=xyz-norm, [3]=pad, [4..67]=points
    __shared__ __align__(16) float h1s[32][64];
    __shared__ float pmax[2][128];

    const int q = blockIdx.x;
    const int b = q >> 10;
    const int t = threadIdx.x;

    // ---- phase A: gather features into LDS (8 threads per sample row) ----
    {
        const int k  = t >> 3;
        const int l8 = t & 7;
        const int gi = gidx[q * 32 + k];
        const float* prow = points + ((size_t)b * NN + gi) * CC;
        const float4 v0 = *(const float4*)(prow + l8 * 8);
        const float4 v1 = *(const float4*)(prow + l8 * 8 + 4);
        *(float4*)&feats[k][4 + l8 * 8] = v0;
        *(float4*)&feats[k][8 + l8 * 8] = v1;
        if (l8 == 0) {
            const float* pr = xyz + ((size_t)b * NN + gi) * 3;
            const float* nr = new_xyz + (size_t)q * 3;
            feats[k][0] = pr[0] - nr[0];
            feats[k][1] = pr[1] - nr[1];
            feats[k][2] = pr[2] - nr[2];
        }
    }

    // w1 row in registers (c1 = t & 63), loaded while feats land in LDS
    const int c1 = t & 63;
    float w1r[67];
    #pragma unroll
    for (int j = 0; j < 67; ++j) w1r[j] = w1[c1 * 67 + j];
    const float bb1 = b1[c1];
    __syncthreads();

    // ---- phase B: layer 1. Wave-uniform k => LDS broadcast reads ----
    const int kg = t >> 6;   // wave id, 0..3
    #pragma unroll
    for (int kk = 0; kk < 8; ++kk) {
        const int kr = kg * 8 + kk;
        float acc = bb1;
        acc += feats[kr][0] * w1r[0] + feats[kr][1] * w1r[1] + feats[kr][2] * w1r[2];
        #pragma unroll
        for (int j = 0; j < 64; j += 4) {
            const float4 f = *(const float4*)&feats[kr][4 + j];
            acc += f.x * w1r[3 + j] + f.y * w1r[4 + j] + f.z * w1r[5 + j] + f.w * w1r[6 + j];
        }
        h1s[kr][c1] = fmaxf(acc, 0.0f);
    }

    // w2 row in registers (o2 = t & 127); k split in halves across thread groups
    const int o2 = t & 127;
    const int kh = t >> 7;   // 0 or 1
    float w2r[64];
    #pragma unroll
    for (int j = 0; j < 64; ++j) w2r[j] = w2[o2 * 64 + j];
    const float bb2 = b2[o2];
    __syncthreads();

    // ---- phase C: layer 2 + running max over k ----
    float mx = -INFINITY;
    #pragma unroll
    for (int kk = 0; kk < 16; ++kk) {
        const int kr = kh * 16 + kk;
        float acc = bb2;
        #pragma unroll
        for (int j = 0; j < 64; j += 4) {
            const float4 h = *(const float4*)&h1s[kr][j];
            acc += h.x * w2r[j] + h.y * w2r[j + 1] + h.z * w2r[j + 2] + h.w * w2r[j + 3];
        }
        mx = fmaxf(mx, fmaxf(acc, 0.0f));
    }
    pmax[kh][o2] = mx;
    __syncthreads();
    if (t < 128) {
        new_points[(size_t)q * 128 + t] = fmaxf(pmax[0][t], pmax[1][t]);
    }
}

// ---------------------------------------------------------------------------
extern "C" void kernel_launch(void* const* d_in, const int* in_sizes, int n_in,
                              void* d_out, int out_size, void* d_ws, size_t ws_size,
                              hipStream_t stream) {
    const float* xyz    = (const float*)d_in[0];   // (4, 16384, 3)
    const float* points = (const float*)d_in[1];   // (4, 16384, 64)
    const float* w1     = (const float*)d_in[2];   // (64, 67)
    const float* b1     = (const float*)d_in[3];   // (64,)
    const float* w2     = (const float*)d_in[4];   // (128, 64)
    const float* b2     = (const float*)d_in[5];   // (128,)
    // d_in[6] = npoint (1024), fixed by the problem setup

    float* out_newxyz    = (float*)d_out;                       // 4*1024*3
    float* out_newpoints = (float*)d_out + (size_t)BB * NPOINT * 3;
    int*   gidx          = (int*)d_ws;                          // 4*1024*32 ints

    fps_kernel<<<BB, FPS_T, 0, stream>>>(xyz, out_newxyz);
    ballq_kernel<<<(BB * NPOINT) / 4, 256, 0, stream>>>(xyz, out_newxyz, gidx);
    mlp_kernel<<<BB * NPOINT, 256, 0, stream>>>(xyz, points, w1, b1, w2, b2,
                                                out_newxyz, gidx, out_newpoints);
}